// Round 1
// baseline (791.003 us; speedup 1.0000x reference)
//
#include <hip/hip_runtime.h>
#include <hip/hip_bf16.h>
#include <stdint.h>

// LinearMultiHeadedAttention: B=16, S=4096, D=1024, H=16, DK=64
// out = ((elu(q)+1) . KV . Z) @ Wo^T + bo  with KV = sum_s (elu(k)+1) (x) v
//
// Plan: bf16 MFMA for the two big projections (137 GF each) + KV (8.6 GF);
// fp32 VALU for the tiny q/x/out stages. Adaptive batch-chunking on ws_size.

using bf16 = __hip_bfloat16;
typedef __attribute__((ext_vector_type(8))) short short8;  // bf16x8 MFMA frag
typedef __attribute__((ext_vector_type(4))) float f32x4;

#define NB_B 16
#define SEQ 4096
#define DM 1024
#define NH 16
#define DKH 64

__device__ __forceinline__ void gload_lds16(const void* g, void* l) {
  __builtin_amdgcn_global_load_lds((const __attribute__((address_space(1))) void*)g,
                                   (__attribute__((address_space(3))) void*)l, 16, 0, 0);
}

// ---------------- fp32 -> bf16 conversion (vector x4) ----------------
__global__ __launch_bounds__(256) void conv_kernel(const float* __restrict__ src,
                                                   bf16* __restrict__ dst, long n4) {
  long i = (long)blockIdx.x * blockDim.x + threadIdx.x;
  const long stride = (long)gridDim.x * blockDim.x;
  for (; i < n4; i += stride) {
    float4 v = ((const float4*)src)[i];
    union { ushort4 u; bf16 h[4]; } o;
    o.h[0] = __float2bfloat16(v.x);
    o.h[1] = __float2bfloat16(v.y);
    o.h[2] = __float2bfloat16(v.z);
    o.h[3] = __float2bfloat16(v.w);
    ((ushort4*)dst)[i] = o.u;
  }
}

// ---------------- projection GEMM (m97-style 128x128 tile) ----------------
// C[row][col] = sum_c A[row][c] * W[col][c]  (+bias[col]); KPROJ: elu+1, Ksum.
// Output stored TRANSPOSED: outT[col][row] (bf16) so the KV kernel reads
// contiguous 16B fragments. A: [rowsTot][DM] bf16. W: [DM][DM] bf16.
template <int KPROJ>
__global__ __launch_bounds__(256) void gemm_proj(
    const bf16* __restrict__ A, const bf16* __restrict__ W,
    const float* __restrict__ bias, bf16* __restrict__ outT,
    float* __restrict__ Ksum, int rowsTot, int b0) {
  __shared__ bf16 As[128 * 64];
  __shared__ bf16 Bs[128 * 64];
  const int tid = threadIdx.x;
  const int lane = tid & 63;
  const int wid = tid >> 6;
  const int wr = wid >> 1, wc = wid & 1;
  const int col0 = blockIdx.x * 128;  // x = col tile (8) -> L2-friendly order
  const int row0 = blockIdx.y * 128;
  f32x4 acc[4][4] = {};
  const int srow = wid * 32 + (lane >> 3);  // staging row (+i*8)
  const int scol = (lane & 7) * 8;          // staging col (bf16 elems)

  for (int kt = 0; kt < DM / 64; ++kt) {
    const int kb = kt * 64;
#pragma unroll
    for (int i = 0; i < 4; ++i) {
      gload_lds16(A + (long)(row0 + srow + i * 8) * DM + kb + scol, &As[(wid * 4 + i) * 512]);
      gload_lds16(W + (long)(col0 + srow + i * 8) * DM + kb + scol, &Bs[(wid * 4 + i) * 512]);
    }
    __syncthreads();
#pragma unroll
    for (int kk = 0; kk < 2; ++kk) {
      short8 af[4], bfv[4];
#pragma unroll
      for (int m = 0; m < 4; ++m)
        af[m] = *(const short8*)&As[(wr * 64 + m * 16 + (lane & 15)) * 64 + kk * 32 + (lane >> 4) * 8];
#pragma unroll
      for (int n = 0; n < 4; ++n)
        bfv[n] = *(const short8*)&Bs[(wc * 64 + n * 16 + (lane & 15)) * 64 + kk * 32 + (lane >> 4) * 8];
#pragma unroll
      for (int m = 0; m < 4; ++m)
#pragma unroll
        for (int n = 0; n < 4; ++n)
          acc[m][n] = __builtin_amdgcn_mfma_f32_16x16x32_bf16(af[m], bfv[n], acc[m][n], 0, 0, 0);
    }
    __syncthreads();
  }

  // epilogue: bias (+ elu+1 + Ksum for KPROJ), bf16, transposed store
  const int bglob = b0 + (row0 >> 12);  // 4096 rows per batch, 128 | 4096
#pragma unroll
  for (int n = 0; n < 4; ++n) {
    const int colg = col0 + wc * 64 + n * 16 + (lane & 15);
    const float bv = bias[colg];
    float csum = 0.f;
#pragma unroll
    for (int m = 0; m < 4; ++m) {
      const int r = row0 + wr * 64 + m * 16 + (lane >> 4) * 4;  // 4 consecutive rows
      union { ushort4 u; bf16 h[4]; } pk;
#pragma unroll
      for (int i = 0; i < 4; ++i) {
        float v = acc[m][n][i] + bv;
        if (KPROJ) { v = v > 0.f ? v + 1.f : __expf(v); csum += v; }
        pk.h[i] = __float2bfloat16(v);
      }
      *(ushort4*)&outT[(long)colg * rowsTot + r] = pk.u;
    }
    if (KPROJ) {
      csum += __shfl_xor(csum, 16);
      csum += __shfl_xor(csum, 32);
      if (lane < 16) atomicAdd(&Ksum[(long)bglob * DM + colg], csum);
    }
  }
}

// ---------------- KV accumulation: KV[b,h] = K^T @ V (64x64, K-dim=S) -------
// KT/VT: [DM][rowsTot] bf16 (transposed). Fragments load straight from global.
__global__ __launch_bounds__(256) void kv_kernel(
    const bf16* __restrict__ KT, const bf16* __restrict__ VT,
    float* __restrict__ KV, int rowsTot, int b0) {
  const int h = blockIdx.x & 15;
  const int b_loc = blockIdx.x >> 4;
  const int lane = threadIdx.x & 63;
  const int w = threadIdx.x >> 6;  // wave owns d-rows [w*16, w*16+16)
  const long srow = (long)b_loc * SEQ + ((lane >> 4) * 8);
  const bf16* Ab = KT + (long)(h * DKH + w * 16 + (lane & 15)) * rowsTot + srow;
  const bf16* Bb = VT + (long)(h * DKH + (lane & 15)) * rowsTot + srow;
  f32x4 acc[4] = {};
#pragma unroll 2
  for (int s = 0; s < SEQ; s += 32) {
    short8 a = *(const short8*)(Ab + s);
#pragma unroll
    for (int n = 0; n < 4; ++n) {
      short8 bv = *(const short8*)(Bb + (long)n * 16 * rowsTot + s);
      acc[n] = __builtin_amdgcn_mfma_f32_16x16x32_bf16(a, bv, acc[n], 0, 0, 0);
    }
  }
  float* o = KV + ((long)(b0 + b_loc) * NH + h) * DKH * DKH;
#pragma unroll
  for (int n = 0; n < 4; ++n)
#pragma unroll
    for (int i = 0; i < 4; ++i)
      o[(w * 16 + (lane >> 4) * 4 + i) * DKH + n * 16 + (lane & 15)] = acc[n][i];
}

// ---------------- small fp32 vec-mat: out[b][n] = in[b][:] . W[n][:] + bias --
template <int ELU>
__global__ __launch_bounds__(256) void vecmat_kernel(
    const float* __restrict__ in, const float* __restrict__ W,
    const float* __restrict__ bias, float* __restrict__ outp) {
  const int b = blockIdx.x >> 5;
  const int n0 = (blockIdx.x & 31) * 32;
  const int lane = threadIdx.x & 63;
  const int w = threadIdx.x >> 6;
  float4 qv[4];
#pragma unroll
  for (int it = 0; it < 4; ++it)
    qv[it] = *(const float4*)&in[(long)b * DM + it * 256 + lane * 4];
#pragma unroll
  for (int j = 0; j < 8; ++j) {
    const int n = n0 + w * 8 + j;
    const float* wrow = W + (long)n * DM;
    float s = 0.f;
#pragma unroll
    for (int it = 0; it < 4; ++it) {
      float4 wv = *(const float4*)&wrow[it * 256 + lane * 4];
      s += qv[it].x * wv.x + qv[it].y * wv.y + qv[it].z * wv.z + qv[it].w * wv.w;
    }
    s += __shfl_xor(s, 1);  s += __shfl_xor(s, 2);  s += __shfl_xor(s, 4);
    s += __shfl_xor(s, 8);  s += __shfl_xor(s, 16); s += __shfl_xor(s, 32);
    if (lane == 0) {
      float v = s + bias[n];
      if (ELU) v = v > 0.f ? v + 1.f : __expf(v);
      outp[(long)b * DM + n] = v;
    }
  }
}

// ---------------- x[b][h*64+m] = (Q[b,h,:] . KV[b,h,:,m]) / (Q . Ksum + eps) -
__global__ __launch_bounds__(256) void xcomp_kernel(
    const float* __restrict__ Q, const float* __restrict__ KV,
    const float* __restrict__ Ksum, float* __restrict__ xb) {
  const int b = blockIdx.x;
  const int t = threadIdx.x;
  const int h = t >> 4;
  const int m0 = (t & 15) * 4;
  const float* q = Q + (long)b * DM + h * DKH;
  const float* ks = Ksum + (long)b * DM + h * DKH;
  const float* kv = KV + ((long)b * NH + h) * DKH * DKH;
  float zden = 0.f;
#pragma unroll
  for (int d = 0; d < DKH; ++d) zden += q[d] * ks[d];
  const float z = 1.f / (zden + 1e-6f);
  float nv[4] = {0.f, 0.f, 0.f, 0.f};
  for (int d = 0; d < DKH; ++d) {
    const float qd = q[d];
#pragma unroll
    for (int j = 0; j < 4; ++j) nv[j] += qd * kv[d * DKH + m0 + j];
  }
  float* xo = xb + (long)b * DM + h * DKH + m0;
#pragma unroll
  for (int j = 0; j < 4; ++j) xo[j] = nv[j] * z;
}

extern "C" void kernel_launch(void* const* d_in, const int* in_sizes, int n_in,
                              void* d_out, int out_size, void* d_ws, size_t ws_size,
                              hipStream_t stream) {
  (void)in_sizes; (void)n_in; (void)out_size;
  const float* query = (const float*)d_in[0];
  const float* key   = (const float*)d_in[1];
  const float* value = (const float*)d_in[2];
  const float* Wq = (const float*)d_in[3];
  const float* bq = (const float*)d_in[4];
  const float* Wk = (const float*)d_in[5];
  const float* bk = (const float*)d_in[6];
  const float* Wv = (const float*)d_in[7];
  const float* bv = (const float*)d_in[8];
  const float* Wo = (const float*)d_in[9];
  const float* bo = (const float*)d_in[10];
  float* out = (float*)d_out;

  char* p = (char*)d_ws;
  bf16* WkB = (bf16*)p;  p += (size_t)DM * DM * 2;
  bf16* WvB = (bf16*)p;  p += (size_t)DM * DM * 2;
  float* KV = (float*)p; p += (size_t)NB_B * NH * DKH * DKH * 4;
  float* Ksum = (float*)p; p += (size_t)NB_B * DM * 4;
  float* Q = (float*)p;  p += (size_t)NB_B * DM * 4;
  float* xb = (float*)p; p += (size_t)NB_B * DM * 4;
  const size_t fixed = (size_t)(p - (char*)d_ws);
  const size_t per_b = (size_t)4 * SEQ * DM * 2;  // keyB+valB+kT+vT per batch
  if (ws_size < fixed + per_b) return;            // cannot run
  int nbc = (int)((ws_size - fixed) / per_b);
  if (nbc > NB_B) nbc = NB_B;
  bf16* keyB = (bf16*)p; p += (size_t)nbc * SEQ * DM * 2;
  bf16* valB = (bf16*)p; p += (size_t)nbc * SEQ * DM * 2;
  bf16* kT   = (bf16*)p; p += (size_t)nbc * SEQ * DM * 2;
  bf16* vT   = (bf16*)p; p += (size_t)nbc * SEQ * DM * 2;

  hipMemsetAsync(Ksum, 0, (size_t)NB_B * DM * 4, stream);
  conv_kernel<<<512, 256, 0, stream>>>(Wk, WkB, (long)DM * DM / 4);
  conv_kernel<<<512, 256, 0, stream>>>(Wv, WvB, (long)DM * DM / 4);
  vecmat_kernel<1><<<NB_B * 32, 256, 0, stream>>>(query, Wq, bq, Q);

  for (int b0 = 0; b0 < NB_B; b0 += nbc) {
    const int nb = (NB_B - b0 < nbc) ? (NB_B - b0) : nbc;
    const int rows = nb * SEQ;
    const long n4 = (long)rows * DM / 4;
    conv_kernel<<<2048, 256, 0, stream>>>(key + (size_t)b0 * SEQ * DM, keyB, n4);
    conv_kernel<<<2048, 256, 0, stream>>>(value + (size_t)b0 * SEQ * DM, valB, n4);
    dim3 g(DM / 128, rows / 128);
    gemm_proj<1><<<g, 256, 0, stream>>>(keyB, WkB, bk, kT, Ksum, rows, b0);
    gemm_proj<0><<<g, 256, 0, stream>>>(valB, WvB, bv, vT, (float*)nullptr, rows, b0);
    kv_kernel<<<nb * NH, 256, 0, stream>>>(kT, vT, KV, rows, b0);
  }

  xcomp_kernel<<<NB_B, 256, 0, stream>>>(Q, KV, Ksum, xb);
  vecmat_kernel<0><<<NB_B * 32, 256, 0, stream>>>(xb, Wo, bo, out);
}

// Round 2
// 708.879 us; speedup vs baseline: 1.1159x; 1.1159x over previous
//
#include <hip/hip_runtime.h>
#include <hip/hip_bf16.h>
#include <stdint.h>

// LinearMultiHeadedAttention: B=16, S=4096, D=1024, H=16, DK=64
// R2: fuse fp32->bf16 into GEMM staging (reg-staged A, swizzled ds_write),
//     T2 XOR-swizzle LDS (B via pre-swizzled global_load_lds source),
//     T1 XCD-aware block swizzle, kv_kernel 4-way S-split.

using bf16 = __hip_bfloat16;
typedef __attribute__((ext_vector_type(8))) short short8;  // bf16x8 MFMA frag
typedef __attribute__((ext_vector_type(4))) float f32x4;

#define NB_B 16
#define SEQ 4096
#define DM 1024
#define NH 16
#define DKH 64

__device__ __forceinline__ void gload_lds16(const void* g, void* l) {
  __builtin_amdgcn_global_load_lds((const __attribute__((address_space(1))) void*)g,
                                   (__attribute__((address_space(3))) void*)l, 16, 0, 0);
}

// ---------------- fp32 -> bf16 conversion (weights only now) ----------------
__global__ __launch_bounds__(256) void conv_kernel(const float* __restrict__ src,
                                                   bf16* __restrict__ dst, long n4) {
  long i = (long)blockIdx.x * blockDim.x + threadIdx.x;
  const long stride = (long)gridDim.x * blockDim.x;
  for (; i < n4; i += stride) {
    float4 v = ((const float4*)src)[i];
    union { ushort4 u; bf16 h[4]; } o;
    o.h[0] = __float2bfloat16(v.x);
    o.h[1] = __float2bfloat16(v.y);
    o.h[2] = __float2bfloat16(v.z);
    o.h[3] = __float2bfloat16(v.w);
    ((ushort4*)dst)[i] = o.u;
  }
}

// ---------------- projection GEMM (128x128 tile, fused cvt, swizzled LDS) ---
// C[row][col] = sum_c A[row][c] * W[col][c]  (+bias[col]); KPROJ: elu+1, Ksum.
// A: fp32 [rowsTot][DM] (key/value directly). W: bf16 [DM][DM].
// Output TRANSPOSED bf16: outT[col][row].
// LDS tiles [128 rows][64 cols bf16] = 128B rows; swizzle: byte ^= (row&7)<<4.
template <int KPROJ>
__global__ __launch_bounds__(256) void gemm_proj(
    const float* __restrict__ A, const bf16* __restrict__ W,
    const float* __restrict__ bias, bf16* __restrict__ outT,
    float* __restrict__ Ksum, int rowsTot, int b0, int chunk) {
  __shared__ bf16 As[128 * 64];
  __shared__ bf16 Bs[128 * 64];
  const int tid = threadIdx.x;
  const int lane = tid & 63;
  const int wid = tid >> 6;
  const int wr = wid >> 1, wc = wid & 1;
  // T1: XCD swizzle. nwg = 8*chunk; XCD gets contiguous row-tile range,
  // col-tile fastest within it -> A panel L2-resident per XCD.
  const int wgid = (blockIdx.x & 7) * chunk + (blockIdx.x >> 3);
  const int row0 = (wgid >> 3) * 128;
  const int col0 = (wgid & 7) * 128;
  f32x4 acc[4][4] = {};

  char* AsB = (char*)As;
  const int str = tid >> 3;                        // staging row-in-group 0..31
  const int sslotA = ((tid & 7) ^ (str & 7));      // swizzled 16B slot (A write)
  const int bsrc = (((lane & 7) ^ (lane >> 3)) * 8);  // pre-swizzled B src (bf16 elems)
  const int xr = (lane & 7) << 4;                  // read-side XOR key
  const int lr = lane & 15;
  const int lk = (lane >> 4) * 16;                 // 16B col-offset base (bytes)

  for (int kt = 0; kt < DM / 64; ++kt) {
    const int kb = kt * 64;
    // B: global_load_lds, linear dest + pre-swizzled per-lane source (m173)
#pragma unroll
    for (int i = 0; i < 4; ++i)
      gload_lds16(W + (long)(col0 + wid * 32 + i * 8 + (lane >> 3)) * DM + kb + bsrc,
                  &Bs[(wid * 4 + i) * 512]);
    // A: fp32 global -> regs -> bf16 -> swizzled ds_write_b128
    float4 fa[4][2];
#pragma unroll
    for (int i = 0; i < 4; ++i) {
      const float* src = A + (long)(row0 + i * 32 + str) * DM + kb + (tid & 7) * 8;
      fa[i][0] = *(const float4*)src;
      fa[i][1] = *(const float4*)(src + 4);
    }
#pragma unroll
    for (int i = 0; i < 4; ++i) {
      union { bf16 h[8]; short8 v; } pk;
      pk.h[0] = __float2bfloat16(fa[i][0].x);
      pk.h[1] = __float2bfloat16(fa[i][0].y);
      pk.h[2] = __float2bfloat16(fa[i][0].z);
      pk.h[3] = __float2bfloat16(fa[i][0].w);
      pk.h[4] = __float2bfloat16(fa[i][1].x);
      pk.h[5] = __float2bfloat16(fa[i][1].y);
      pk.h[6] = __float2bfloat16(fa[i][1].z);
      pk.h[7] = __float2bfloat16(fa[i][1].w);
      *(short8*)(AsB + (i * 32 + str) * 128 + (sslotA << 4)) = pk.v;
    }
    __syncthreads();
#pragma unroll
    for (int kk = 0; kk < 2; ++kk) {
      short8 af[4], bfv[4];
#pragma unroll
      for (int m = 0; m < 4; ++m) {
        const int row = wr * 64 + m * 16 + lr;
        af[m] = *(const short8*)(AsB + row * 128 + ((kk * 64 + lk) ^ xr));
      }
#pragma unroll
      for (int n = 0; n < 4; ++n) {
        const int row = wc * 64 + n * 16 + lr;
        bfv[n] = *(const short8*)((char*)Bs + row * 128 + ((kk * 64 + lk) ^ xr));
      }
#pragma unroll
      for (int m = 0; m < 4; ++m)
#pragma unroll
        for (int n = 0; n < 4; ++n)
          acc[m][n] = __builtin_amdgcn_mfma_f32_16x16x32_bf16(af[m], bfv[n], acc[m][n], 0, 0, 0);
    }
    __syncthreads();
  }

  // epilogue: bias (+ elu+1 + Ksum for KPROJ), bf16, transposed store
  const int bglob = b0 + (row0 >> 12);  // 128 | 4096 -> row-tile within one batch
#pragma unroll
  for (int n = 0; n < 4; ++n) {
    const int colg = col0 + wc * 64 + n * 16 + (lane & 15);
    const float bv = bias[colg];
    float csum = 0.f;
#pragma unroll
    for (int m = 0; m < 4; ++m) {
      const int r = row0 + wr * 64 + m * 16 + (lane >> 4) * 4;  // 4 consecutive rows
      union { ushort4 u; bf16 h[4]; } pk;
#pragma unroll
      for (int i = 0; i < 4; ++i) {
        float v = acc[m][n][i] + bv;
        if (KPROJ) { v = v > 0.f ? v + 1.f : __expf(v); csum += v; }
        pk.h[i] = __float2bfloat16(v);
      }
      *(ushort4*)&outT[(long)colg * rowsTot + r] = pk.u;
    }
    if (KPROJ) {
      csum += __shfl_xor(csum, 16);
      csum += __shfl_xor(csum, 32);
      if (lane < 16) atomicAdd(&Ksum[(long)bglob * DM + colg], csum);
    }
  }
}

// ---------------- KV partials: KVp[sp,b,h] = K^T @ V over s-range ----------
// KT/VT: [DM][rowsTot] bf16 (transposed). 4-way S-split for occupancy.
__global__ __launch_bounds__(256) void kv_kernel(
    const bf16* __restrict__ KT, const bf16* __restrict__ VT,
    float* __restrict__ KVp, int rowsTot, int b0) {
  const int sp = blockIdx.x & 3;
  const int h = (blockIdx.x >> 2) & 15;
  const int b_loc = blockIdx.x >> 6;
  const int lane = threadIdx.x & 63;
  const int w = threadIdx.x >> 6;  // wave owns d-rows [w*16, w*16+16)
  const long srow = (long)b_loc * SEQ + sp * (SEQ / 4) + ((lane >> 4) * 8);
  const bf16* Ab = KT + (long)(h * DKH + w * 16 + (lane & 15)) * rowsTot + srow;
  const bf16* Bb = VT + (long)(h * DKH + (lane & 15)) * rowsTot + srow;
  f32x4 acc[4] = {};
#pragma unroll 2
  for (int s = 0; s < SEQ / 4; s += 32) {
    short8 a = *(const short8*)(Ab + s);
#pragma unroll
    for (int n = 0; n < 4; ++n) {
      short8 bv = *(const short8*)(Bb + (long)n * 16 * rowsTot + s);
      acc[n] = __builtin_amdgcn_mfma_f32_16x16x32_bf16(a, bv, acc[n], 0, 0, 0);
    }
  }
  float* o = KVp + (((long)sp * NB_B + (b0 + b_loc)) * NH + h) * DKH * DKH;
#pragma unroll
  for (int n = 0; n < 4; ++n)
#pragma unroll
    for (int i = 0; i < 4; ++i)
      o[(w * 16 + (lane >> 4) * 4 + i) * DKH + n * 16 + (lane & 15)] = acc[n][i];
}

// ---------------- small fp32 vec-mat: out[b][n] = in[b][:] . W[n][:] + bias --
template <int ELU>
__global__ __launch_bounds__(256) void vecmat_kernel(
    const float* __restrict__ in, const float* __restrict__ W,
    const float* __restrict__ bias, float* __restrict__ outp) {
  const int b = blockIdx.x >> 5;
  const int n0 = (blockIdx.x & 31) * 32;
  const int lane = threadIdx.x & 63;
  const int w = threadIdx.x >> 6;
  float4 qv[4];
#pragma unroll
  for (int it = 0; it < 4; ++it)
    qv[it] = *(const float4*)&in[(long)b * DM + it * 256 + lane * 4];
#pragma unroll
  for (int j = 0; j < 8; ++j) {
    const int n = n0 + w * 8 + j;
    const float* wrow = W + (long)n * DM;
    float s = 0.f;
#pragma unroll
    for (int it = 0; it < 4; ++it) {
      float4 wv = *(const float4*)&wrow[it * 256 + lane * 4];
      s += qv[it].x * wv.x + qv[it].y * wv.y + qv[it].z * wv.z + qv[it].w * wv.w;
    }
    s += __shfl_xor(s, 1);  s += __shfl_xor(s, 2);  s += __shfl_xor(s, 4);
    s += __shfl_xor(s, 8);  s += __shfl_xor(s, 16); s += __shfl_xor(s, 32);
    if (lane == 0) {
      float v = s + bias[n];
      if (ELU) v = v > 0.f ? v + 1.f : __expf(v);
      outp[(long)b * DM + n] = v;
    }
  }
}

// ---- x[b][h*64+m] = (Q[b,h,:] . KV[b,h,:,m]) / (Q . Ksum + eps); KV = sum of 4 partials
__global__ __launch_bounds__(256) void xcomp_kernel(
    const float* __restrict__ Q, const float* __restrict__ KVp,
    const float* __restrict__ Ksum, float* __restrict__ xb) {
  const int b = blockIdx.x;
  const int t = threadIdx.x;
  const int h = t >> 4;
  const int m0 = (t & 15) * 4;
  const float* q = Q + (long)b * DM + h * DKH;
  const float* ks = Ksum + (long)b * DM + h * DKH;
  const long kvoff = ((long)b * NH + h) * DKH * DKH;
  const long spstride = (long)NB_B * NH * DKH * DKH;
  float zden = 0.f;
#pragma unroll
  for (int d = 0; d < DKH; ++d) zden += q[d] * ks[d];
  const float z = 1.f / (zden + 1e-6f);
  float nv[4] = {0.f, 0.f, 0.f, 0.f};
  for (int d = 0; d < DKH; ++d) {
    const float qd = q[d];
#pragma unroll
    for (int j = 0; j < 4; ++j) {
      const long idx = kvoff + d * DKH + m0 + j;
      nv[j] += qd * (KVp[idx] + KVp[idx + spstride] +
                     KVp[idx + 2 * spstride] + KVp[idx + 3 * spstride]);
    }
  }
  float* xo = xb + (long)b * DM + h * DKH + m0;
#pragma unroll
  for (int j = 0; j < 4; ++j) xo[j] = nv[j] * z;
}

extern "C" void kernel_launch(void* const* d_in, const int* in_sizes, int n_in,
                              void* d_out, int out_size, void* d_ws, size_t ws_size,
                              hipStream_t stream) {
  (void)in_sizes; (void)n_in; (void)out_size;
  const float* query = (const float*)d_in[0];
  const float* key   = (const float*)d_in[1];
  const float* value = (const float*)d_in[2];
  const float* Wq = (const float*)d_in[3];
  const float* bq = (const float*)d_in[4];
  const float* Wk = (const float*)d_in[5];
  const float* bk = (const float*)d_in[6];
  const float* Wv = (const float*)d_in[7];
  const float* bv = (const float*)d_in[8];
  const float* Wo = (const float*)d_in[9];
  const float* bo = (const float*)d_in[10];
  float* out = (float*)d_out;

  char* p = (char*)d_ws;
  bf16* WkB = (bf16*)p;  p += (size_t)DM * DM * 2;
  bf16* WvB = (bf16*)p;  p += (size_t)DM * DM * 2;
  float* KVp = (float*)p; p += (size_t)4 * NB_B * NH * DKH * DKH * 4;
  float* Ksum = (float*)p; p += (size_t)NB_B * DM * 4;
  float* Q = (float*)p;  p += (size_t)NB_B * DM * 4;
  float* xb = (float*)p; p += (size_t)NB_B * DM * 4;
  const size_t fixed = (size_t)(p - (char*)d_ws);
  const size_t per_b = (size_t)2 * SEQ * DM * 2;  // kT+vT per batch (bf16)
  if (ws_size < fixed + per_b) return;            // cannot run
  int nbc = (int)((ws_size - fixed) / per_b);
  if (nbc > NB_B) nbc = NB_B;
  bf16* kT = (bf16*)p; p += (size_t)nbc * SEQ * DM * 2;
  bf16* vT = (bf16*)p; p += (size_t)nbc * SEQ * DM * 2;

  hipMemsetAsync(Ksum, 0, (size_t)NB_B * DM * 4, stream);
  conv_kernel<<<512, 256, 0, stream>>>(Wk, WkB, (long)DM * DM / 4);
  conv_kernel<<<512, 256, 0, stream>>>(Wv, WvB, (long)DM * DM / 4);
  vecmat_kernel<1><<<NB_B * 32, 256, 0, stream>>>(query, Wq, bq, Q);

  for (int b0 = 0; b0 < NB_B; b0 += nbc) {
    const int nb = (NB_B - b0 < nbc) ? (NB_B - b0) : nbc;
    const int rows = nb * SEQ;
    const int nwg = (rows / 128) * 8;
    gemm_proj<1><<<nwg, 256, 0, stream>>>(key + (size_t)b0 * SEQ * DM, WkB, bk, kT, Ksum, rows, b0, nwg / 8);
    gemm_proj<0><<<nwg, 256, 0, stream>>>(value + (size_t)b0 * SEQ * DM, WvB, bv, vT, (float*)nullptr, rows, b0, nwg / 8);
    kv_kernel<<<nb * NH * 4, 256, 0, stream>>>(kT, vT, KVp, rows, b0);
  }

  xcomp_kernel<<<NB_B, 256, 0, stream>>>(Q, KVp, Ksum, xb);
  vecmat_kernel<0><<<NB_B * 32, 256, 0, stream>>>(xb, Wo, bo, out);
}

// Round 3
// 641.457 us; speedup vs baseline: 1.2331x; 1.1051x over previous
//
#include <hip/hip_runtime.h>
#include <hip/hip_bf16.h>
#include <stdint.h>

// LinearMultiHeadedAttention: B=16, S=4096, D=1024, H=16, DK=64
// R3: double-buffered LDS + counted-vmcnt pipeline (T3min+T4+T14).
//     Per K-step: ONE raw barrier; A fp32 loads fly across it (vmcnt(8)),
//     only the 4 B gload_lds drain. cvt+ds_write after MFMA phase.

using bf16 = __hip_bfloat16;
typedef __attribute__((ext_vector_type(8))) short short8;  // bf16x8 MFMA frag
typedef __attribute__((ext_vector_type(4))) float f32x4;

#define NB_B 16
#define SEQ 4096
#define DM 1024
#define NH 16
#define DKH 64

__device__ __forceinline__ void gload_lds16(const void* g, void* l) {
  __builtin_amdgcn_global_load_lds((const __attribute__((address_space(1))) void*)g,
                                   (__attribute__((address_space(3))) void*)l, 16, 0, 0);
}

__device__ __forceinline__ short8 pack_bf16x8(float4 a, float4 b) {
  union { bf16 h[8]; short8 v; } pk;
  pk.h[0] = __float2bfloat16(a.x); pk.h[1] = __float2bfloat16(a.y);
  pk.h[2] = __float2bfloat16(a.z); pk.h[3] = __float2bfloat16(a.w);
  pk.h[4] = __float2bfloat16(b.x); pk.h[5] = __float2bfloat16(b.y);
  pk.h[6] = __float2bfloat16(b.z); pk.h[7] = __float2bfloat16(b.w);
  return pk.v;
}

// ---------------- fp32 -> bf16 conversion (weights only) ----------------
__global__ __launch_bounds__(256) void conv_kernel(const float* __restrict__ src,
                                                   bf16* __restrict__ dst, long n4) {
  long i = (long)blockIdx.x * blockDim.x + threadIdx.x;
  const long stride = (long)gridDim.x * blockDim.x;
  for (; i < n4; i += stride) {
    float4 v = ((const float4*)src)[i];
    union { ushort4 u; bf16 h[4]; } o;
    o.h[0] = __float2bfloat16(v.x);
    o.h[1] = __float2bfloat16(v.y);
    o.h[2] = __float2bfloat16(v.z);
    o.h[3] = __float2bfloat16(v.w);
    ((ushort4*)dst)[i] = o.u;
  }
}

// ---------------- projection GEMM (128x128, dbuf LDS, counted vmcnt) -------
// C[row][col] = sum_c A[row][c] * W[col][c]  (+bias[col]); KPROJ: elu+1, Ksum.
// A: fp32 [rowsTot][DM]. W: bf16 [DM][DM]. Out TRANSPOSED bf16 outT[col][row].
// LDS tiles [128][64] bf16, XOR-swizzle byte ^= (row&7)<<4 on both tiles.
template <int KPROJ>
__global__ __launch_bounds__(256) void gemm_proj(
    const float* __restrict__ A, const bf16* __restrict__ W,
    const float* __restrict__ bias, bf16* __restrict__ outT,
    float* __restrict__ Ksum, int rowsTot, int b0, int chunk) {
  __shared__ bf16 As[2][128 * 64];
  __shared__ bf16 Bs[2][128 * 64];
  const int tid = threadIdx.x;
  const int lane = tid & 63;
  const int wid = tid >> 6;
  const int wr = wid >> 1, wc = wid & 1;
  // T1 XCD swizzle: XCD gets contiguous row-tile range, col-tile fastest.
  const int wgid = (blockIdx.x & 7) * chunk + (blockIdx.x >> 3);
  const int row0 = (wgid >> 3) * 128;
  const int col0 = (wgid & 7) * 128;
  f32x4 acc[4][4] = {};

  const int str = tid >> 3;                       // A staging row 0..31 (+i*32)
  const int sslotA = ((tid & 7) ^ (str & 7)) << 4;  // swizzled byte slot
  const int acol = (tid & 7) * 8;                 // A src col (fp32)
  const int bsrc = ((lane & 7) ^ (lane >> 3)) * 8;  // pre-swizzled B src col
  const int xr = (lane & 7) << 4;                 // read-side XOR key
  const int lr = lane & 15;
  const int lk = (lane >> 4) * 16;

  const float* Arow[4];
#pragma unroll
  for (int i = 0; i < 4; ++i) Arow[i] = A + (long)(row0 + i * 32 + str) * DM + acol;
  const bf16* Wrow = W + (long)(col0 + wid * 32 + (lane >> 3)) * DM + bsrc;

  float4 fa[4][2];
  // ---- prologue: A(0) regs first (oldest), then B(0) gload_lds
#pragma unroll
  for (int i = 0; i < 4; ++i) {
    fa[i][0] = *(const float4*)(Arow[i]);
    fa[i][1] = *(const float4*)(Arow[i] + 4);
  }
#pragma unroll
  for (int i = 0; i < 4; ++i)
    gload_lds16(Wrow + i * 8 * DM, &Bs[0][(wid * 4 + i) * 512]);
#pragma unroll
  for (int i = 0; i < 4; ++i)
    *(short8*)((char*)As[0] + (i * 32 + str) * 128 + sslotA) = pack_bf16x8(fa[i][0], fa[i][1]);
#pragma unroll
  for (int i = 0; i < 4; ++i) {  // preload fa <- A(1)
    fa[i][0] = *(const float4*)(Arow[i] + 64);
    fa[i][1] = *(const float4*)(Arow[i] + 68);
  }
  // outstanding: fa(A1)=8 newest + B(0)=4 oldest? (B issued after A(0) regs,
  // before fa(A1)) -> oldest 4 of 12 are B(0): drain them, keep fa flying.
  asm volatile("s_waitcnt vmcnt(8) lgkmcnt(0)\n\ts_barrier" ::: "memory");
  __builtin_amdgcn_sched_barrier(0);

  for (int kt = 0; kt < 16; ++kt) {
    const int cur = kt & 1;
    bf16* Asc = As[cur];
    bf16* Bsc = Bs[cur];
    bf16* Asn = As[cur ^ 1];
    if (kt < 15) {  // stage B(kt+1)
      const int kb = (kt + 1) * 64;
#pragma unroll
      for (int i = 0; i < 4; ++i)
        gload_lds16(Wrow + kb + i * 8 * DM, &Bs[cur ^ 1][(wid * 4 + i) * 512]);
    }
    // compute tile kt
#pragma unroll
    for (int kk = 0; kk < 2; ++kk) {
      short8 af[4], bfv[4];
#pragma unroll
      for (int m = 0; m < 4; ++m)
        af[m] = *(const short8*)((char*)Asc + (wr * 64 + m * 16 + lr) * 128 + ((kk * 64 + lk) ^ xr));
#pragma unroll
      for (int n = 0; n < 4; ++n)
        bfv[n] = *(const short8*)((char*)Bsc + (wc * 64 + n * 16 + lr) * 128 + ((kk * 64 + lk) ^ xr));
#pragma unroll
      for (int m = 0; m < 4; ++m)
#pragma unroll
        for (int n = 0; n < 4; ++n)
          acc[m][n] = __builtin_amdgcn_mfma_f32_16x16x32_bf16(af[m], bfv[n], acc[m][n], 0, 0, 0);
    }
    if (kt < 15) {
      // cvt A(kt+1) (in flight since last iter) -> swizzled ds_write
#pragma unroll
      for (int i = 0; i < 4; ++i)
        *(short8*)((char*)Asn + (i * 32 + str) * 128 + sslotA) = pack_bf16x8(fa[i][0], fa[i][1]);
      if (kt < 14) {  // reissue fa <- A(kt+2)
        const int ka = (kt + 2) * 64;
#pragma unroll
        for (int i = 0; i < 4; ++i) {
          fa[i][0] = *(const float4*)(Arow[i] + ka);
          fa[i][1] = *(const float4*)(Arow[i] + ka + 4);
        }
        // outstanding: B(kt+1)=4 oldest + fa=8 -> drain B only
        asm volatile("s_waitcnt vmcnt(8) lgkmcnt(0)\n\ts_barrier" ::: "memory");
      } else {
        asm volatile("s_waitcnt vmcnt(0) lgkmcnt(0)\n\ts_barrier" ::: "memory");
      }
      __builtin_amdgcn_sched_barrier(0);
    }
  }

  // epilogue: bias (+ elu+1 + Ksum for KPROJ), bf16, transposed store
  const int bglob = b0 + (row0 >> 12);
#pragma unroll
  for (int n = 0; n < 4; ++n) {
    const int colg = col0 + wc * 64 + n * 16 + (lane & 15);
    const float bv = bias[colg];
    float csum = 0.f;
#pragma unroll
    for (int m = 0; m < 4; ++m) {
      const int r = row0 + wr * 64 + m * 16 + (lane >> 4) * 4;
      union { ushort4 u; bf16 h[4]; } pk;
#pragma unroll
      for (int i = 0; i < 4; ++i) {
        float v = acc[m][n][i] + bv;
        if (KPROJ) { v = v > 0.f ? v + 1.f : __expf(v); csum += v; }
        pk.h[i] = __float2bfloat16(v);
      }
      *(ushort4*)&outT[(long)colg * rowsTot + r] = pk.u;
    }
    if (KPROJ) {
      csum += __shfl_xor(csum, 16);
      csum += __shfl_xor(csum, 32);
      if (lane < 16) atomicAdd(&Ksum[(long)bglob * DM + colg], csum);
    }
  }
}

// ---------------- KV partials: KVp[sp,b,h] = K^T @ V over s-range ----------
__global__ __launch_bounds__(256) void kv_kernel(
    const bf16* __restrict__ KT, const bf16* __restrict__ VT,
    float* __restrict__ KVp, int rowsTot, int b0) {
  const int sp = blockIdx.x & 3;
  const int h = (blockIdx.x >> 2) & 15;
  const int b_loc = blockIdx.x >> 6;
  const int lane = threadIdx.x & 63;
  const int w = threadIdx.x >> 6;
  const long srow = (long)b_loc * SEQ + sp * (SEQ / 4) + ((lane >> 4) * 8);
  const bf16* Ab = KT + (long)(h * DKH + w * 16 + (lane & 15)) * rowsTot + srow;
  const bf16* Bb = VT + (long)(h * DKH + (lane & 15)) * rowsTot + srow;
  f32x4 acc[4] = {};
#pragma unroll 2
  for (int s = 0; s < SEQ / 4; s += 32) {
    short8 a = *(const short8*)(Ab + s);
#pragma unroll
    for (int n = 0; n < 4; ++n) {
      short8 bv = *(const short8*)(Bb + (long)n * 16 * rowsTot + s);
      acc[n] = __builtin_amdgcn_mfma_f32_16x16x32_bf16(a, bv, acc[n], 0, 0, 0);
    }
  }
  float* o = KVp + (((long)sp * NB_B + (b0 + b_loc)) * NH + h) * DKH * DKH;
#pragma unroll
  for (int n = 0; n < 4; ++n)
#pragma unroll
    for (int i = 0; i < 4; ++i)
      o[(w * 16 + (lane >> 4) * 4 + i) * DKH + n * 16 + (lane & 15)] = acc[n][i];
}

// ---------------- small fp32 vec-mat ----------------
template <int ELU>
__global__ __launch_bounds__(256) void vecmat_kernel(
    const float* __restrict__ in, const float* __restrict__ W,
    const float* __restrict__ bias, float* __restrict__ outp) {
  const int b = blockIdx.x >> 5;
  const int n0 = (blockIdx.x & 31) * 32;
  const int lane = threadIdx.x & 63;
  const int w = threadIdx.x >> 6;
  float4 qv[4];
#pragma unroll
  for (int it = 0; it < 4; ++it)
    qv[it] = *(const float4*)&in[(long)b * DM + it * 256 + lane * 4];
#pragma unroll
  for (int j = 0; j < 8; ++j) {
    const int n = n0 + w * 8 + j;
    const float* wrow = W + (long)n * DM;
    float s = 0.f;
#pragma unroll
    for (int it = 0; it < 4; ++it) {
      float4 wv = *(const float4*)&wrow[it * 256 + lane * 4];
      s += qv[it].x * wv.x + qv[it].y * wv.y + qv[it].z * wv.z + qv[it].w * wv.w;
    }
    s += __shfl_xor(s, 1);  s += __shfl_xor(s, 2);  s += __shfl_xor(s, 4);
    s += __shfl_xor(s, 8);  s += __shfl_xor(s, 16); s += __shfl_xor(s, 32);
    if (lane == 0) {
      float v = s + bias[n];
      if (ELU) v = v > 0.f ? v + 1.f : __expf(v);
      outp[(long)b * DM + n] = v;
    }
  }
}

// ---- x = (Q . KV) * Z with KV = sum of 4 partials
__global__ __launch_bounds__(256) void xcomp_kernel(
    const float* __restrict__ Q, const float* __restrict__ KVp,
    const float* __restrict__ Ksum, float* __restrict__ xb) {
  const int b = blockIdx.x;
  const int t = threadIdx.x;
  const int h = t >> 4;
  const int m0 = (t & 15) * 4;
  const float* q = Q + (long)b * DM + h * DKH;
  const float* ks = Ksum + (long)b * DM + h * DKH;
  const long kvoff = ((long)b * NH + h) * DKH * DKH;
  const long spstride = (long)NB_B * NH * DKH * DKH;
  float zden = 0.f;
#pragma unroll
  for (int d = 0; d < DKH; ++d) zden += q[d] * ks[d];
  const float z = 1.f / (zden + 1e-6f);
  float nv[4] = {0.f, 0.f, 0.f, 0.f};
  for (int d = 0; d < DKH; ++d) {
    const float qd = q[d];
#pragma unroll
    for (int j = 0; j < 4; ++j) {
      const long idx = kvoff + d * DKH + m0 + j;
      nv[j] += qd * (KVp[idx] + KVp[idx + spstride] +
                     KVp[idx + 2 * spstride] + KVp[idx + 3 * spstride]);
    }
  }
  float* xo = xb + (long)b * DM + h * DKH + m0;
#pragma unroll
  for (int j = 0; j < 4; ++j) xo[j] = nv[j] * z;
}

extern "C" void kernel_launch(void* const* d_in, const int* in_sizes, int n_in,
                              void* d_out, int out_size, void* d_ws, size_t ws_size,
                              hipStream_t stream) {
  (void)in_sizes; (void)n_in; (void)out_size;
  const float* query = (const float*)d_in[0];
  const float* key   = (const float*)d_in[1];
  const float* value = (const float*)d_in[2];
  const float* Wq = (const float*)d_in[3];
  const float* bq = (const float*)d_in[4];
  const float* Wk = (const float*)d_in[5];
  const float* bk = (const float*)d_in[6];
  const float* Wv = (const float*)d_in[7];
  const float* bv = (const float*)d_in[8];
  const float* Wo = (const float*)d_in[9];
  const float* bo = (const float*)d_in[10];
  float* out = (float*)d_out;

  char* p = (char*)d_ws;
  bf16* WkB = (bf16*)p;  p += (size_t)DM * DM * 2;
  bf16* WvB = (bf16*)p;  p += (size_t)DM * DM * 2;
  float* KVp = (float*)p; p += (size_t)4 * NB_B * NH * DKH * DKH * 4;
  float* Ksum = (float*)p; p += (size_t)NB_B * DM * 4;
  float* Q = (float*)p;  p += (size_t)NB_B * DM * 4;
  float* xb = (float*)p; p += (size_t)NB_B * DM * 4;
  const size_t fixed = (size_t)(p - (char*)d_ws);
  const size_t per_b = (size_t)2 * SEQ * DM * 2;  // kT+vT per batch (bf16)
  if (ws_size < fixed + per_b) return;
  int nbc = (int)((ws_size - fixed) / per_b);
  if (nbc > NB_B) nbc = NB_B;
  bf16* kT = (bf16*)p; p += (size_t)nbc * SEQ * DM * 2;
  bf16* vT = (bf16*)p; p += (size_t)nbc * SEQ * DM * 2;

  hipMemsetAsync(Ksum, 0, (size_t)NB_B * DM * 4, stream);
  conv_kernel<<<512, 256, 0, stream>>>(Wk, WkB, (long)DM * DM / 4);
  conv_kernel<<<512, 256, 0, stream>>>(Wv, WvB, (long)DM * DM / 4);
  vecmat_kernel<1><<<NB_B * 32, 256, 0, stream>>>(query, Wq, bq, Q);

  for (int b0 = 0; b0 < NB_B; b0 += nbc) {
    const int nb = (NB_B - b0 < nbc) ? (NB_B - b0) : nbc;
    const int rows = nb * SEQ;
    const int nwg = (rows / 128) * 8;
    gemm_proj<1><<<nwg, 256, 0, stream>>>(key + (size_t)b0 * SEQ * DM, WkB, bk, kT, Ksum, rows, b0, nwg / 8);
    gemm_proj<0><<<nwg, 256, 0, stream>>>(value + (size_t)b0 * SEQ * DM, WvB, bv, vT, (float*)nullptr, rows, b0, nwg / 8);
    kv_kernel<<<nb * NH * 4, 256, 0, stream>>>(kT, vT, KVp, rows, b0);
  }

  xcomp_kernel<<<NB_B, 256, 0, stream>>>(Q, KVp, Ksum, xb);
  vecmat_kernel<0><<<NB_B * 32, 256, 0, stream>>>(xb, Wo, bo, out);
}